// Round 6
// baseline (262.488 us; speedup 1.0000x reference)
//
#include <hip/hip_runtime.h>
#include <hip/hip_bf16.h>

#define NE 32
#define MM 1024
#define KK 512
#define NN 512
#define BM 64    // rows per tile
#define BN 128   // cols per tile -> 4 n-tiles
#define BK 32    // K-step per iteration (16 iterations)

typedef __attribute__((ext_vector_type(8))) short bf16x8;
typedef __attribute__((ext_vector_type(4))) float floatx4;

__device__ __forceinline__ short f2bf(float f) {
  union { __hip_bfloat16 b; short s; } u;
  u.b = __float2bfloat16(f);   // RNE
  return u.s;
}

// ZERO-LDS / ZERO-BARRIER kernel. MFMA A/B fragments are built directly from
// global: lane needs 8 consecutive k-floats of one row = two adjacent float4
// loads (32 contiguous bytes). No staging round-trip, no __syncthreads, no
// lockstep: every wave pipelines its own loads independently; per-block
// duplicate reads (A shared by wave pairs {0,1},{2,3}, B by {0,2},{1,3})
// are same-iteration -> L1-served. Cross-block reuse stays in the XCD L2
// via the pinned decode below.
extern "C" __global__ __launch_bounds__(256, 3)
void expert_gemm(const float* __restrict__ A, const float* __restrict__ B,
                 const int* __restrict__ cnts, float* __restrict__ C)
{
  const int b    = blockIdx.x;
  const int tid  = threadIdx.x;
  const int xcd  = b & 7;
  const int slot = b >> 3;

  int e = -1, mt = 0, nt = 0, zfill = 0;
  int base = 0;
#pragma unroll
  for (int i = 0; i < 4; ++i) {
    int ei = xcd + (i << 3);
    int vt = (cnts[ei] + 63) >> 6;
    int tot = 16 + 3 * vt;
    if (e < 0 && slot < base + tot) {
      int r = slot - base;
      int g = vt << 2;
      e = ei;
      if (r < g) { mt = r >> 2; nt = r & 3; }
      else       { zfill = 1; mt = vt + (r - g); }
    }
    base += tot;
  }
  if (e < 0) return;

  if (zfill) {
    // zero-fill a 64x512 stripe (harness poisons d_out each launch)
    float* Ce = C + ((size_t)e * MM + mt * BM) * NN;
    float4 zf = make_float4(0.f, 0.f, 0.f, 0.f);
#pragma unroll
    for (int i = 0; i < 32; ++i) {
      int fidx = i * 256 + tid;
      int r = fidx >> 7, c = (fidx & 127) << 2;
      *(float4*)(Ce + (size_t)r * NN + c) = zf;
    }
    return;
  }

  // ---- GEMM tile: C[e][m0:m0+64][n0:n0+128] = A[e] @ B[e]^T ----
  const int m0 = mt * BM, n0 = nt * BN;
  const int cnt = cnts[e];
  const float* Ae = A + ((size_t)e * MM + m0) * KK;
  const float* Be = B + ((size_t)e * NN + n0) * KK;
  float* Ce = C + ((size_t)e * MM + m0) * NN + n0;

  const int wave = tid >> 6, lane = tid & 63;
  const int wm = (wave >> 1) * 32, wn = (wave & 1) * 64;  // wave tile: 32x64
  const int fr = lane & 15, kh = lane >> 4;

  // per-lane row base pointers (fragment layout: lane holds row `fr`-ish,
  // k-slice [kh*8, kh*8+8) of each 16-row fragment)
  const float* pA0 = Ae + (size_t)(wm + fr)      * KK + (kh << 3);
  const float* pA1 = Ae + (size_t)(wm + 16 + fr) * KK + (kh << 3);
  const float* pB0 = Be + (size_t)(wn + fr)      * KK + (kh << 3);
  const float* pB1 = Be + (size_t)(wn + 16 + fr) * KK + (kh << 3);
  const float* pB2 = Be + (size_t)(wn + 32 + fr) * KK + (kh << 3);
  const float* pB3 = Be + (size_t)(wn + 48 + fr) * KK + (kh << 3);

  floatx4 acc4[2][4] = {};

  // register prefetch, distance = 1 K-step; no barrier exists to drain it
  float4 ra[4], rb[8], na[4], nb[8];

#define ISSUE(pa, pb, kt_) do {                                    \
    pa[0] = *(const float4*)(pA0 + (kt_));                         \
    pa[1] = *(const float4*)(pA0 + (kt_) + 4);                     \
    pa[2] = *(const float4*)(pA1 + (kt_));                         \
    pa[3] = *(const float4*)(pA1 + (kt_) + 4);                     \
    pb[0] = *(const float4*)(pB0 + (kt_));                         \
    pb[1] = *(const float4*)(pB0 + (kt_) + 4);                     \
    pb[2] = *(const float4*)(pB1 + (kt_));                         \
    pb[3] = *(const float4*)(pB1 + (kt_) + 4);                     \
    pb[4] = *(const float4*)(pB2 + (kt_));                         \
    pb[5] = *(const float4*)(pB2 + (kt_) + 4);                     \
    pb[6] = *(const float4*)(pB3 + (kt_));                         \
    pb[7] = *(const float4*)(pB3 + (kt_) + 4);                     \
  } while (0)

  ISSUE(ra, rb, 0);

#pragma unroll
  for (int kt = 0; kt < KK; kt += BK) {
    if (kt + BK < KK) ISSUE(na, nb, kt + BK);   // in flight across cvt+MFMA

    bf16x8 af[2], bfv[4];
#pragma unroll
    for (int i = 0; i < 2; ++i) {
      float4 f0 = ra[i * 2], f1 = ra[i * 2 + 1];
      af[i] = (bf16x8){ f2bf(f0.x), f2bf(f0.y), f2bf(f0.z), f2bf(f0.w),
                        f2bf(f1.x), f2bf(f1.y), f2bf(f1.z), f2bf(f1.w) };
    }
#pragma unroll
    for (int j = 0; j < 4; ++j) {
      float4 f0 = rb[j * 2], f1 = rb[j * 2 + 1];
      bfv[j] = (bf16x8){ f2bf(f0.x), f2bf(f0.y), f2bf(f0.z), f2bf(f0.w),
                         f2bf(f1.x), f2bf(f1.y), f2bf(f1.z), f2bf(f1.w) };
    }

#pragma unroll
    for (int i = 0; i < 2; ++i)
#pragma unroll
      for (int j = 0; j < 4; ++j)
        acc4[i][j] = __builtin_amdgcn_mfma_f32_16x16x32_bf16(af[i], bfv[j], acc4[i][j], 0, 0, 0);

    // rotate prefetch buffers (renamed away by full unroll)
#pragma unroll
    for (int q = 0; q < 4; ++q) ra[q] = na[q];
#pragma unroll
    for (int q = 0; q < 8; ++q) rb[q] = nb[q];
  }
#undef ISSUE

  // epilogue: C/D layout col=lane&15, row=(lane>>4)*4+reg (m89/m91-verified)
  const int rbase = (lane >> 4) * 4;
#pragma unroll
  for (int i = 0; i < 2; ++i) {
#pragma unroll
    for (int r = 0; r < 4; ++r) {
      int row = wm + i * 16 + rbase + r;
      bool valid = (m0 + row) < cnt;
#pragma unroll
      for (int j = 0; j < 4; ++j) {
        int col = wn + j * 16 + fr;
        Ce[(size_t)row * NN + col] = valid ? acc4[i][j][r] : 0.0f;
      }
    }
  }
}

extern "C" void kernel_launch(void* const* d_in, const int* in_sizes, int n_in,
                              void* d_out, int out_size, void* d_ws, size_t ws_size,
                              hipStream_t stream) {
  const float* A    = (const float*)d_in[0];
  const float* B    = (const float*)d_in[1];
  const int*   cnts = (const int*)d_in[2];
  float*       C    = (float*)d_out;

  // 8 XCDs x 256 slots; blockIdx & 7 selects XCD (round-robin dispatch)
  hipLaunchKernelGGL(expert_gemm, dim3(2048), dim3(256), 0, stream, A, B, cnts, C);
}

// Round 7
// 173.351 us; speedup vs baseline: 1.5142x; 1.5142x over previous
//
#include <hip/hip_runtime.h>
#include <hip/hip_bf16.h>

#define NE 32
#define MM 1024
#define KK 512
#define NN 512
#define BM 64    // rows per tile
#define BN 128   // cols per tile -> 4 n-tiles
#define BK 32    // fp32 elems per LDS row = 128 B = 8 x 16B units, XOR-swizzled

typedef __attribute__((ext_vector_type(8))) short bf16x8;
typedef __attribute__((ext_vector_type(4))) float floatx4;

__device__ __forceinline__ short f2bf(float f) {
  union { __hip_bfloat16 b; short s; } u;
  u.b = __float2bfloat16(f);   // RNE
  return u.s;
}

// Fire-and-forget global->LDS DMA (16 B/lane). Linear LDS dest (HW: uniform
// base + lane*16); bank-conflict swizzle applied on the SOURCE address and
// mirrored on the ds_read side (both-sides-or-neither, verified rounds 4-5).
#define GLDS(g, l) __builtin_amdgcn_global_load_lds(                      \
    (const __attribute__((address_space(1))) void*)(g),                   \
    (__attribute__((address_space(3))) void*)(l), 16, 0, 0)

// XCD-partitioned decode: xcd = blockIdx.x & 7, slot = blockIdx.x >> 3.
// XCD x owns experts {x, x+8, x+16, x+24}; per expert (expert-major):
//   [4*vt GEMM tiles (mt-major, nt fastest)] ++ [(16-vt) zero 64x512 stripes]
extern "C" __global__ __launch_bounds__(256, 2)
void expert_gemm(const float* __restrict__ A, const float* __restrict__ B,
                 const int* __restrict__ cnts, float* __restrict__ C)
{
  const int b    = blockIdx.x;
  const int tid  = threadIdx.x;
  const int xcd  = b & 7;
  const int slot = b >> 3;

  int e = -1, mt = 0, nt = 0, zfill = 0;
  int base = 0;
#pragma unroll
  for (int i = 0; i < 4; ++i) {
    int ei = xcd + (i << 3);
    int vt = (cnts[ei] + 63) >> 6;
    int tot = 16 + 3 * vt;
    if (e < 0 && slot < base + tot) {
      int r = slot - base;
      int g = vt << 2;
      e = ei;
      if (r < g) { mt = r >> 2; nt = r & 3; }
      else       { zfill = 1; mt = vt + (r - g); }
    }
    base += tot;
  }
  if (e < 0) return;

  if (zfill) {
    // zero-fill a 64x512 stripe (harness poisons d_out each launch)
    float* Ce = C + ((size_t)e * MM + mt * BM) * NN;
    float4 zf = make_float4(0.f, 0.f, 0.f, 0.f);
#pragma unroll
    for (int i = 0; i < 32; ++i) {
      int fidx = i * 256 + tid;
      int r = fidx >> 7, c = (fidx & 127) << 2;
      *(float4*)(Ce + (size_t)r * NN + c) = zf;
    }
    return;
  }

  // ---- GEMM tile: C[e][m0:m0+64][n0:n0+128] = A[e] @ B[e]^T ----
  const int m0 = mt * BM, n0 = nt * BN;
  const int cnt = cnts[e];
  const float* Ae = A + ((size_t)e * MM + m0) * KK;
  const float* Be = B + ((size_t)e * NN + n0) * KK;
  float* Ce = C + ((size_t)e * MM + m0) * NN + n0;

  // fp32 staging, TRIPLE-buffered (pipeline depth 2: while computing slab k,
  // slabs k+1 and k+2 are in flight). Row = 32 floats = 128 B = 8x16B units;
  // logical unit u of row r lives at phys unit u ^ (r&7).
  __shared__ __align__(16) float sA[3][BM * BK];  // 3 x 8 KB
  __shared__ __align__(16) float sB[3][BN * BK];  // 3 x 16 KB

  const int wave = tid >> 6, lane = tid & 63;
  const int wm = (wave >> 1) * 32, wn = (wave & 1) * 64;  // wave tile: 32x64
  const int fr = lane & 15, kh = lane >> 4;
  const int frs = fr & 7;              // row-swizzle key for frag reads

  // DMA source geometry: each issue covers 8 rows x 128 B = 1 KB per wave.
  const int lr = lane >> 3;
  const int lu = (lane & 7) ^ lr;
  const size_t rowb = (size_t)lr * (KK * 4) + (size_t)lu * 16;  // bytes
  const char* gA = (const char*)Ae;
  const char* gB = (const char*)Be;

  // Per slab: 24 wave-DMAs (A:8, B:16) split 6 per wave.
#define STAGE(bufi, KT) do {                                               \
    _Pragma("unroll")                                                      \
    for (int q = 0; q < 2; ++q) {                                          \
      int ia = wave + (q << 2);                                            \
      GLDS(gA + (size_t)(8 * ia) * (KK * 4) + rowb + (size_t)(KT) * 4,     \
           &sA[bufi][ia << 8]);                                            \
    }                                                                      \
    _Pragma("unroll")                                                      \
    for (int q = 0; q < 4; ++q) {                                          \
      int ib = wave + (q << 2);                                            \
      GLDS(gB + (size_t)(8 * ib) * (KK * 4) + rowb + (size_t)(KT) * 4,     \
           &sB[bufi][ib << 8]);                                            \
    }                                                                      \
  } while (0)

  floatx4 acc4[2][4] = {};

  STAGE(0, 0);          // slab 0: 6 DMAs/wave
  STAGE(1, BK);         // slab 1: 6 more (12 outstanding/wave)

#pragma unroll
  for (int kt = 0; kt < KK; kt += BK) {
    const int it  = kt >> 5;         // 0..15 (static under full unroll)
    const int cur = it % 3;

    if (kt + 2 * BK < KK) {
      STAGE((it + 2) % 3, kt + 2 * BK);   // 18 outstanding/wave
      // wait ONLY slab k (oldest 6); slabs k+1,k+2 (12) stay in flight
      asm volatile("s_waitcnt vmcnt(12)" ::: "memory");
    } else if (kt + BK < KK) {
      asm volatile("s_waitcnt vmcnt(6)" ::: "memory");
    } else {
      asm volatile("s_waitcnt vmcnt(0)" ::: "memory");
    }
    __builtin_amdgcn_s_barrier();        // raw: no compiler vmcnt(0) drain
    __builtin_amdgcn_sched_barrier(0);   // no ds_read hoisted above barrier

    const char* bufA = (const char*)sA[cur];
    const char* bufB = (const char*)sB[cur];

    bf16x8 af[2], bfv[4];
#pragma unroll
    for (int i = 0; i < 2; ++i) {
      int rA = wm + (i << 4) + fr;                 // rA&7 == frs
      const char* rb = bufA + rA * 128;
      float4 f0 = *(const float4*)(rb + ((((kh << 1)    ) ^ frs) << 4));
      float4 f1 = *(const float4*)(rb + ((((kh << 1) | 1) ^ frs) << 4));
      af[i] = (bf16x8){ f2bf(f0.x), f2bf(f0.y), f2bf(f0.z), f2bf(f0.w),
                        f2bf(f1.x), f2bf(f1.y), f2bf(f1.z), f2bf(f1.w) };
    }
#pragma unroll
    for (int j = 0; j < 4; ++j) {
      int rB = wn + (j << 4) + fr;                 // rB&7 == frs
      const char* rb = bufB + rB * 128;
      float4 f0 = *(const float4*)(rb + ((((kh << 1)    ) ^ frs) << 4));
      float4 f1 = *(const float4*)(rb + ((((kh << 1) | 1) ^ frs) << 4));
      bfv[j] = (bf16x8){ f2bf(f0.x), f2bf(f0.y), f2bf(f0.z), f2bf(f0.w),
                         f2bf(f1.x), f2bf(f1.y), f2bf(f1.z), f2bf(f1.w) };
    }
#pragma unroll
    for (int i = 0; i < 2; ++i)
#pragma unroll
      for (int j = 0; j < 4; ++j)
        acc4[i][j] = __builtin_amdgcn_mfma_f32_16x16x32_bf16(af[i], bfv[j], acc4[i][j], 0, 0, 0);

    if (kt + 3 * BK < KK) {
      // next iteration stages into buffer (it+3)%3 == cur, the one just read:
      // all waves must be done reading it first.
      __builtin_amdgcn_sched_barrier(0);  // reads stay above the end barrier
      __builtin_amdgcn_s_barrier();
      __builtin_amdgcn_sched_barrier(0);  // next STAGE stays below it
    }
  }
#undef STAGE

  // epilogue: C/D layout col=lane&15, row=(lane>>4)*4+reg (m89/m91-verified)
  const int rbase = (lane >> 4) * 4;
#pragma unroll
  for (int i = 0; i < 2; ++i) {
#pragma unroll
    for (int r = 0; r < 4; ++r) {
      int row = wm + i * 16 + rbase + r;
      bool valid = (m0 + row) < cnt;
#pragma unroll
      for (int j = 0; j < 4; ++j) {
        int col = wn + j * 16 + fr;
        Ce[(size_t)row * NN + col] = valid ? acc4[i][j][r] : 0.0f;
      }
    }
  }
}

extern "C" void kernel_launch(void* const* d_in, const int* in_sizes, int n_in,
                              void* d_out, int out_size, void* d_ws, size_t ws_size,
                              hipStream_t stream) {
  const float* A    = (const float*)d_in[0];
  const float* B    = (const float*)d_in[1];
  const int*   cnts = (const int*)d_in[2];
  float*       C    = (float*)d_out;

  // 8 XCDs x 256 slots; blockIdx & 7 selects XCD (round-robin dispatch)
  hipLaunchKernelGGL(expert_gemm, dim3(2048), dim3(256), 0, stream, A, B, cnts, C);
}

// Round 8
// 149.240 us; speedup vs baseline: 1.7588x; 1.1616x over previous
//
#include <hip/hip_runtime.h>
#include <hip/hip_bf16.h>

#define NE 32
#define MM 1024
#define KK 512
#define NN 512
#define BM 256   // rows per tile (vt = ceil(cnt/256) m-tiles per expert)
#define BN 256   // cols per tile -> 2 n-tiles
#define BK 32    // K-step; 16 iterations, ONE barrier each

typedef __attribute__((ext_vector_type(8))) short bf16x8;
typedef __attribute__((ext_vector_type(4))) float floatx4;

__device__ __forceinline__ short f2bf(float f) {
  union { __hip_bfloat16 b; short s; } u;
  u.b = __float2bfloat16(f);   // RNE
  return u.s;
}
__device__ __forceinline__ bf16x8 pack8(float4 a, float4 b) {
  return (bf16x8){ f2bf(a.x), f2bf(a.y), f2bf(a.z), f2bf(a.w),
                   f2bf(b.x), f2bf(b.y), f2bf(b.z), f2bf(b.w) };
}

// FAT-TILE structure (m201/m233 lesson): per-barrier-phase overhead is fixed,
// so amortize it -- 256x256 tile, 8 waves, 32 MFMA/wave/phase, 16 phases.
// Per expert (XCD-pinned: expert e -> XCD e&7): items = [2*vt GEMM tiles
// (mt-major, nt fastest)] ++ [(4-vt) zero 256x512 stripes]; vt+4 <= 8 items
// -> <=32 slots/XCD, grid 256, <=1 block/CU: perfectly balanced.
extern "C" __global__ __launch_bounds__(512, 2)
void expert_gemm(const float* __restrict__ A, const float* __restrict__ B,
                 const int* __restrict__ cnts, float* __restrict__ C)
{
  const int b    = blockIdx.x;
  const int tid  = threadIdx.x;
  const int xcd  = b & 7;
  const int slot = b >> 3;

  int e = -1, mt = 0, nt = 0, zfill = 0;
  int base = 0;
#pragma unroll
  for (int i = 0; i < 4; ++i) {
    int ei = xcd + (i << 3);
    int vt = (cnts[ei] + 255) >> 8;    // 256-row tiles with valid rows
    int tot = vt + 4;                  // 2*vt gemm + (4-vt) zero stripes
    if (e < 0 && slot < base + tot) {
      int r = slot - base;
      int g = vt << 1;
      e = ei;
      if (r < g) { mt = r >> 1; nt = r & 1; }
      else       { zfill = 1; mt = vt + (r - g); }
    }
    base += tot;
  }
  if (e < 0) return;   // beyond this XCD's item count (uniform per block)

  if (zfill) {
    // zero-fill a 256x512 stripe (harness poisons d_out each launch)
    float* Ce = C + ((size_t)e * MM + mt * BM) * NN;
    float4 zf = make_float4(0.f, 0.f, 0.f, 0.f);
#pragma unroll
    for (int q = 0; q < 64; ++q) {
      int fidx = q * 512 + tid;
      int r = fidx >> 7, c = (fidx & 127) << 2;
      *(float4*)(Ce + (size_t)r * NN + c) = zf;
    }
    return;
  }

  // ---- GEMM tile: C[e][m0:m0+256][n0:n0+256] = A[e] @ B[e]^T ----
  const int m0 = mt * BM, n0 = nt * BN;
  const int cnt = cnts[e];
  const float* Ae = A + ((size_t)e * MM + m0) * KK;
  const float* Be = B + ((size_t)e * NN + n0) * KK;
  float* Ce = C + ((size_t)e * MM + m0) * NN + n0;

  // bf16 LDS, double-buffered. Row = 32 bf16 = 64 B = 4 x 16B units;
  // logical unit u of row r at phys unit r*4 + (u ^ (r&3)) (verified r0-r2).
  __shared__ __align__(16) short lA[2][BM * BK];  // 2 x 16 KB
  __shared__ __align__(16) short lB[2][BN * BK];  // 2 x 16 KB

  const int wave = tid >> 6, lane = tid & 63;
  const int wm = (wave >> 2) * 128, wn = (wave & 3) * 64;  // wave tile: 128x64
  const int fr = lane & 15, kh = lane >> 4;

  // staging map: thread t -> rows {t>>2, t>>2+128}, seg t&3 (8 floats each)
  const int row0 = tid >> 2, seg = tid & 3;
  const int wu0 = (row0 << 2) + (seg ^ (row0 & 3));           // write unit, row0
  const int wu1 = ((row0 + 128) << 2) + (seg ^ (row0 & 3));   // row0+128 (same key)

  floatx4 acc4[8][4] = {};

  // register prefetch, distance = 1 K-step. The lgkmcnt(0) memory-clobber asm
  // below is a compiler memory fence: the next slab's global loads cannot be
  // sunk past it (fixes r1/r6 load-sinking). Compiler emits exact counted
  // vmcnt waits for these register loads natively.
  float4 ca[4], cb[4], na_[4], nb_[4];

#define ISSUE(pa, pb, KT) do {                                        \
    int colf = (KT) + (seg << 3);                                     \
    pa[0] = *(const float4*)(Ae + (size_t)row0 * KK + colf);          \
    pa[1] = *(const float4*)(Ae + (size_t)row0 * KK + colf + 4);      \
    pa[2] = *(const float4*)(Ae + (size_t)(row0+128) * KK + colf);    \
    pa[3] = *(const float4*)(Ae + (size_t)(row0+128) * KK + colf+4);  \
    pb[0] = *(const float4*)(Be + (size_t)row0 * KK + colf);          \
    pb[1] = *(const float4*)(Be + (size_t)row0 * KK + colf + 4);      \
    pb[2] = *(const float4*)(Be + (size_t)(row0+128) * KK + colf);    \
    pb[3] = *(const float4*)(Be + (size_t)(row0+128) * KK + colf+4);  \
  } while (0)

  ISSUE(ca, cb, 0);

#pragma unroll
  for (int kt = 0; kt < KK; kt += BK) {
    const int cur = (kt >> 5) & 1;
    if (kt + BK < KK) ISSUE(na_, nb_, kt + BK);   // stays in flight past barrier

    // convert + stage current slab (compiler waits exactly ca/cb's vmcnt)
    *(bf16x8*)(lA[cur] + (wu0 << 3)) = pack8(ca[0], ca[1]);
    *(bf16x8*)(lA[cur] + (wu1 << 3)) = pack8(ca[2], ca[3]);
    *(bf16x8*)(lB[cur] + (wu0 << 3)) = pack8(cb[0], cb[1]);
    *(bf16x8*)(lB[cur] + (wu1 << 3)) = pack8(cb[2], cb[3]);

    // ONE barrier per K-step: lgkmcnt(0) drains this wave's ds_writes (and its
    // previous-iter ds_reads), so after the barrier (a) buf[cur] is fully
    // written, (b) buf[cur^1] (written 2 iters ahead) is free of readers.
    asm volatile("s_waitcnt lgkmcnt(0)" ::: "memory");
    __builtin_amdgcn_s_barrier();
    __builtin_amdgcn_sched_barrier(0);

    bf16x8 bfv[4];
#pragma unroll
    for (int j = 0; j < 4; ++j) {
      int rB = wn + (j << 4) + fr;
      bfv[j] = *(const bf16x8*)(lB[cur] + (((rB << 2) + (kh ^ (rB & 3))) << 3));
    }
    __builtin_amdgcn_s_setprio(1);
#pragma unroll
    for (int i = 0; i < 8; ++i) {
      int rA = wm + (i << 4) + fr;
      bf16x8 af = *(const bf16x8*)(lA[cur] + (((rA << 2) + (kh ^ (rA & 3))) << 3));
#pragma unroll
      for (int j = 0; j < 4; ++j)
        acc4[i][j] = __builtin_amdgcn_mfma_f32_16x16x32_bf16(af, bfv[j], acc4[i][j], 0, 0, 0);
    }
    __builtin_amdgcn_s_setprio(0);

    // rotate prefetch buffers (renamed away by full unroll)
#pragma unroll
    for (int q = 0; q < 4; ++q) { ca[q] = na_[q]; cb[q] = nb_[q]; }
  }
#undef ISSUE

  // epilogue: C/D layout col=lane&15, row=(lane>>4)*4+reg (m89/m91-verified)
  const int rbase = (lane >> 4) << 2;
#pragma unroll
  for (int i = 0; i < 8; ++i) {
#pragma unroll
    for (int r = 0; r < 4; ++r) {
      int row = wm + (i << 4) + rbase + r;
      bool valid = (m0 + row) < cnt;
#pragma unroll
      for (int j = 0; j < 4; ++j) {
        int col = wn + (j << 4) + fr;
        Ce[(size_t)row * NN + col] = valid ? acc4[i][j][r] : 0.0f;
      }
    }
  }
}

extern "C" void kernel_launch(void* const* d_in, const int* in_sizes, int n_in,
                              void* d_out, int out_size, void* d_ws, size_t ws_size,
                              hipStream_t stream) {
  const float* A    = (const float*)d_in[0];
  const float* B    = (const float*)d_in[1];
  const int*   cnts = (const int*)d_in[2];
  float*       C    = (float*)d_out;

  // 8 XCDs x <=32 slots; blockIdx & 7 selects XCD (round-robin dispatch)
  hipLaunchKernelGGL(expert_gemm, dim3(256), dim3(512), 0, stream, A, B, cnts, C);
}